// Round 5
// baseline (238.152 us; speedup 1.0000x reference)
//
#include <hip/hip_runtime.h>
#include <hip/hip_bf16.h>

#define B_   4
#define H_   16
#define S_   2048
#define DK_  64
#define NBH  64
// scale = 1/sqrt(64) * log2(e), folded into Q so P = exp2(S - m) directly
#define QSCALE (0.125f * 1.44269504f)

typedef __attribute__((ext_vector_type(8)))  short    short8;
typedef __attribute__((ext_vector_type(16))) float    f32x16;
typedef __attribute__((ext_vector_type(4)))  unsigned u32x4;

__device__ __forceinline__ unsigned short f2bf(float f) {
    union { float f; unsigned int u; } x; x.f = f;
    unsigned int r = x.u + 0x7fffu + ((x.u >> 16) & 1u);
    return (unsigned short)(r >> 16);
}
__device__ __forceinline__ unsigned cvtpk(float a, float b) {
    unsigned r;
    asm("v_cvt_pk_bf16_f32 %0, %1, %2" : "=v"(r) : "v"(a), "v"(b));
    return r;
}
__device__ __forceinline__ void pl32swap(unsigned& a, unsigned& b) {
    asm("v_permlane32_swap_b32 %0, %1" : "+v"(a), "+v"(b));
}

// ---- pre-pass 1: K f32 -> bf16 ----
__global__ __launch_bounds__(256) void conv_k(const float* __restrict__ in,
                                              unsigned short* __restrict__ out) {
    const long i = (long)(blockIdx.x * 256 + threadIdx.x) * 8;
    const float4* p = (const float4*)(in + i);
    float4 a = p[0], b = p[1];
    short8 f;
    f[0] = (short)f2bf(a.x); f[1] = (short)f2bf(a.y);
    f[2] = (short)f2bf(a.z); f[3] = (short)f2bf(a.w);
    f[4] = (short)f2bf(b.x); f[5] = (short)f2bf(b.y);
    f[6] = (short)f2bf(b.z); f[7] = (short)f2bf(b.w);
    *(short8*)(out + i) = f;
}

// ---- pre-pass 2: V f32 [bh][s][d] -> bf16 V^T [bh][d][s] ----
__global__ __launch_bounds__(256) void transp_v(const float* __restrict__ v,
                                                unsigned short* __restrict__ vt) {
    const int s0 = blockIdx.x * 64;
    const int bh = blockIdx.y;
    const int s  = threadIdx.x & 63;
    const int dq = threadIdx.x >> 6;
    const float* src = v + ((long)bh * S_ + s0 + s) * DK_;
    unsigned short* dst = vt + (long)bh * DK_ * S_ + s0 + s;
    #pragma unroll
    for (int j4 = 0; j4 < 4; ++j4) {
        const int d4 = dq * 16 + j4 * 4;
        float4 a = *(const float4*)(src + d4);
        dst[(long)(d4 + 0) * S_] = f2bf(a.x);
        dst[(long)(d4 + 1) * S_] = f2bf(a.y);
        dst[(long)(d4 + 2) * S_] = f2bf(a.z);
        dst[(long)(d4 + 3) * S_] = f2bf(a.w);
    }
}

// ---- main attention: swapped QK^T, 32x32x16, in-reg softmax, double-buffered LDS ----
template <bool PRECONV>
__global__ __launch_bounds__(256, 4) void attn_fwd4(
    const float* __restrict__ q, const float* __restrict__ k32,
    const float* __restrict__ v32, const unsigned short* __restrict__ kbf,
    const unsigned short* __restrict__ vtbf, const int* __restrict__ sen_len,
    float* __restrict__ out)
{
    const int qt = (S_ / 128 - 1) - blockIdx.x;   // heavy tiles first
    const int bh = blockIdx.y;
    const int b  = bh >> 4;
    const int q0 = qt * 128;
    const long base   = (long)bh * S_ * DK_;
    const long vtbase = (long)bh * DK_ * S_;

    const int tid  = threadIdx.x;
    const int wid  = tid >> 6;
    const int lane = tid & 63;
    const int l31  = lane & 31;
    const int hi   = lane >> 5;

    // double-buffered, 64 rows x 128B each, swizzled byte ^= (row&7)<<4
    __shared__ unsigned short Klds[2][64 * 64];
    __shared__ unsigned short Vlds[2][64 * 64];

    const int slen = sen_len[b];
    const int q0w  = q0 + wid * 32;
    const int iq   = q0w + l31;

    // ---- Q fragments: B-frag B[n=q][kd], kd = ks*16 + hi*8 + i ----
    short8 qf[4];
    {
        const float* qp = q + base + (long)iq * DK_ + hi * 8;
        #pragma unroll
        for (int ks = 0; ks < 4; ++ks) {
            float4 a = *(const float4*)(qp + ks * 16);
            float4 c = *(const float4*)(qp + ks * 16 + 4);
            short8 f;
            f[0] = (short)f2bf(a.x * QSCALE); f[1] = (short)f2bf(a.y * QSCALE);
            f[2] = (short)f2bf(a.z * QSCALE); f[3] = (short)f2bf(a.w * QSCALE);
            f[4] = (short)f2bf(c.x * QSCALE); f[5] = (short)f2bf(c.y * QSCALE);
            f[6] = (short)f2bf(c.z * QSCALE); f[7] = (short)f2bf(c.w * QSCALE);
            qf[ks] = f;
        }
    }

    f32x16 O0 = (f32x16)(0.f), O1 = (f32x16)(0.f);
    float m_ = -INFINITY, l_ = 0.f;

    const int nk     = min(q0 + 128, slen);
    const int ntiles = (nk + 63) >> 6;
    const int wmax   = q0w + 31;

    // ---- prologue: stage tile 0 into buffer 0 ----
    if (PRECONV) {
        const unsigned short* ksrc = kbf + base;
        const unsigned short* vsrc = vtbf + vtbase;
        #pragma unroll
        for (int it = 0; it < 2; ++it) {
            const int c = tid + 256 * it, r = c >> 3, slot = c & 7;
            const int dst = r * 128 + ((slot * 16) ^ ((r & 7) << 4));
            *(short8*)((char*)Klds[0] + dst) = *(const short8*)(ksrc + r * DK_ + slot * 8);
            *(short8*)((char*)Vlds[0] + dst) = *(const short8*)(vsrc + (long)r * S_ + slot * 8);
        }
    } else {
        const float* ks32 = k32 + base;
        #pragma unroll
        for (int it = 0; it < 2; ++it) {
            const int c = tid + 256 * it, r = c >> 3, slot = c & 7;
            const float4* p = (const float4*)(ks32 + r * DK_ + slot * 8);
            float4 a = p[0], bq = p[1];
            short8 f;
            f[0] = (short)f2bf(a.x);  f[1] = (short)f2bf(a.y);
            f[2] = (short)f2bf(a.z);  f[3] = (short)f2bf(a.w);
            f[4] = (short)f2bf(bq.x); f[5] = (short)f2bf(bq.y);
            f[6] = (short)f2bf(bq.z); f[7] = (short)f2bf(bq.w);
            *(short8*)((char*)Klds[0] + r * 128 + ((slot * 16) ^ ((r & 7) << 4))) = f;
        }
        const float* vs32 = v32 + base;
        #pragma unroll
        for (int it = 0; it < 4; ++it) {
            const int c = tid + 256 * it, s = c >> 4, d4 = (c & 15) * 4;
            float4 a = *(const float4*)(vs32 + s * DK_ + d4);
            unsigned short vals[4] = {f2bf(a.x), f2bf(a.y), f2bf(a.z), f2bf(a.w)};
            #pragma unroll
            for (int j = 0; j < 4; ++j)
                *(unsigned short*)((char*)Vlds[0] + (d4 + j) * 128 +
                                   ((2 * s) ^ (((d4 + j) & 7) << 4))) = vals[j];
        }
    }
    __syncthreads();

    int cur = 0;
    for (int t = 0; t < ntiles; ++t) {
        const int k0 = t * 64;
        const bool more = (t + 1 < ntiles);

        // ---- issue next-tile global loads (early) ----
        short8 kst[2], vst[2];
        float4 kr[2][2], vr[4];
        if (more) {
            if (PRECONV) {
                const unsigned short* ksrc = kbf + base + (long)(k0 + 64) * DK_;
                const unsigned short* vsrc = vtbf + vtbase + (k0 + 64);
                #pragma unroll
                for (int it = 0; it < 2; ++it) {
                    const int c = tid + 256 * it, r = c >> 3, slot = c & 7;
                    kst[it] = *(const short8*)(ksrc + r * DK_ + slot * 8);
                    vst[it] = *(const short8*)(vsrc + (long)r * S_ + slot * 8);
                }
            } else {
                const float* ks32 = k32 + base + (long)(k0 + 64) * DK_;
                #pragma unroll
                for (int it = 0; it < 2; ++it) {
                    const int c = tid + 256 * it, r = c >> 3, slot = c & 7;
                    kr[it][0] = *(const float4*)(ks32 + r * DK_ + slot * 8);
                    kr[it][1] = *(const float4*)(ks32 + r * DK_ + slot * 8 + 4);
                }
                const float* vs32 = v32 + base + (long)(k0 + 64) * DK_;
                #pragma unroll
                for (int it = 0; it < 4; ++it) {
                    const int c = tid + 256 * it, s = c >> 4, d4 = (c & 15) * 4;
                    vr[it] = *(const float4*)(vs32 + s * DK_ + d4);
                }
            }
        }
        __builtin_amdgcn_sched_barrier(0);

        // ---- compute tile t from buf[cur] ----
        if (k0 <= wmax) {
            const char* KB = (const char*)Klds[cur];
            const char* VB = (const char*)Vlds[cur];
            const int sw = (l31 & 7) << 4;
            const int rb = l31 * 128;

            f32x16 s0 = (f32x16)(0.f), s1 = (f32x16)(0.f);
            __builtin_amdgcn_s_setprio(1);
            #pragma unroll
            for (int ks = 0; ks < 4; ++ks) {
                const int col = (ks * 32 + hi * 16) ^ sw;
                short8 kf0 = *(const short8*)(KB + rb + col);
                short8 kf1 = *(const short8*)(KB + 4096 + rb + col);
                s0 = __builtin_amdgcn_mfma_f32_32x32x16_bf16(kf0, qf[ks], s0, 0, 0, 0);
                s1 = __builtin_amdgcn_mfma_f32_32x32x16_bf16(kf1, qf[ks], s1, 0, 0, 0);
            }
            __builtin_amdgcn_s_setprio(0);

            // ---- mask (skip for interior fully-valid tiles) ----
            if (!((k0 + 63 <= q0w) && (k0 + 63 < slen))) {
                #pragma unroll
                for (int r = 0; r < 16; ++r) {
                    const int joff = k0 + (r & 3) + 8 * (r >> 2) + 4 * hi;
                    if (!((joff <= iq) && (joff < slen))) s0[r] = -1e30f;
                    if (!((joff + 32 <= iq) && (joff + 32 < slen))) s1[r] = -1e30f;
                }
            }

            // ---- online softmax: tree max, defer-max rescale, 4-way sums ----
            float x[16];
            #pragma unroll
            for (int i = 0; i < 16; ++i) x[i] = fmaxf(s0[i], s1[i]);
            #pragma unroll
            for (int st = 8; st >= 1; st >>= 1)
                #pragma unroll
                for (int i = 0; i < 8; ++i)
                    if (i < st) x[i] = fmaxf(x[i], x[i + st]);
            float pm = x[0];
            pm = fmaxf(pm, __shfl_xor(pm, 32, 64));
            if (!__all(pm <= m_ + 8.0f)) {
                const float mn = fmaxf(m_, pm);
                const float rc = exp2f(m_ - mn);
                m_ = mn; l_ *= rc;
                O0 *= rc; O1 *= rc;
            }
            float rs[4] = {0.f, 0.f, 0.f, 0.f};
            #pragma unroll
            for (int i = 0; i < 16; ++i) { s0[i] = exp2f(s0[i] - m_); rs[i & 3] += s0[i]; }
            #pragma unroll
            for (int i = 0; i < 16; ++i) { s1[i] = exp2f(s1[i] - m_); rs[i & 3] += s1[i]; }
            float rsum = (rs[0] + rs[1]) + (rs[2] + rs[3]);
            rsum += __shfl_xor(rsum, 32, 64);
            l_ += rsum;

            // ---- P -> bf16 B-frags in-register ----
            u32x4 pw[4];
            {
                unsigned a0 = cvtpk(s0[0], s0[1]),  c0 = cvtpk(s0[2], s0[3]);
                unsigned b0 = cvtpk(s0[4], s0[5]),  d0 = cvtpk(s0[6], s0[7]);
                pl32swap(a0, b0); pl32swap(c0, d0);
                pw[0] = (u32x4){a0, c0, b0, d0};
                unsigned a1 = cvtpk(s0[8], s0[9]),   c1 = cvtpk(s0[10], s0[11]);
                unsigned b1 = cvtpk(s0[12], s0[13]), d1 = cvtpk(s0[14], s0[15]);
                pl32swap(a1, b1); pl32swap(c1, d1);
                pw[1] = (u32x4){a1, c1, b1, d1};
                unsigned a2 = cvtpk(s1[0], s1[1]),  c2 = cvtpk(s1[2], s1[3]);
                unsigned b2 = cvtpk(s1[4], s1[5]),  d2 = cvtpk(s1[6], s1[7]);
                pl32swap(a2, b2); pl32swap(c2, d2);
                pw[2] = (u32x4){a2, c2, b2, d2};
                unsigned a3 = cvtpk(s1[8], s1[9]),   c3 = cvtpk(s1[10], s1[11]);
                unsigned b3 = cvtpk(s1[12], s1[13]), d3 = cvtpk(s1[14], s1[15]);
                pl32swap(a3, b3); pl32swap(c3, d3);
                pw[3] = (u32x4){a3, c3, b3, d3};
            }

            // ---- PV: O[64d x 32q] += V^T[d][k] * P[k][q] ----
            __builtin_amdgcn_s_setprio(1);
            #pragma unroll
            for (int s = 0; s < 4; ++s) {
                short8 pf = __builtin_bit_cast(short8, pw[s]);
                const int col = (s * 32 + hi * 16) ^ sw;
                short8 vf0 = *(const short8*)(VB + rb + col);
                short8 vf1 = *(const short8*)(VB + 4096 + rb + col);
                O0 = __builtin_amdgcn_mfma_f32_32x32x16_bf16(vf0, pf, O0, 0, 0, 0);
                O1 = __builtin_amdgcn_mfma_f32_32x32x16_bf16(vf1, pf, O1, 0, 0, 0);
            }
            __builtin_amdgcn_s_setprio(0);
        }
        __builtin_amdgcn_sched_barrier(0);

        // ---- write staged tile t+1 into buf[cur^1], single barrier ----
        if (more) {
            char* KB = (char*)Klds[cur ^ 1];
            char* VB = (char*)Vlds[cur ^ 1];
            if (PRECONV) {
                #pragma unroll
                for (int it = 0; it < 2; ++it) {
                    const int c = tid + 256 * it, r = c >> 3, slot = c & 7;
                    const int dst = r * 128 + ((slot * 16) ^ ((r & 7) << 4));
                    *(short8*)(KB + dst) = kst[it];
                    *(short8*)(VB + dst) = vst[it];
                }
            } else {
                #pragma unroll
                for (int it = 0; it < 2; ++it) {
                    const int c = tid + 256 * it, r = c >> 3, slot = c & 7;
                    float4 a = kr[it][0], bq = kr[it][1];
                    short8 f;
                    f[0] = (short)f2bf(a.x);  f[1] = (short)f2bf(a.y);
                    f[2] = (short)f2bf(a.z);  f[3] = (short)f2bf(a.w);
                    f[4] = (short)f2bf(bq.x); f[5] = (short)f2bf(bq.y);
                    f[6] = (short)f2bf(bq.z); f[7] = (short)f2bf(bq.w);
                    *(short8*)(KB + r * 128 + ((slot * 16) ^ ((r & 7) << 4))) = f;
                }
                #pragma unroll
                for (int it = 0; it < 4; ++it) {
                    const int c = tid + 256 * it, s = c >> 4, d4 = (c & 15) * 4;
                    float4 a = vr[it];
                    unsigned short vals[4] = {f2bf(a.x), f2bf(a.y), f2bf(a.z), f2bf(a.w)};
                    #pragma unroll
                    for (int j = 0; j < 4; ++j)
                        *(unsigned short*)(VB + (d4 + j) * 128 +
                                           ((2 * s) ^ (((d4 + j) & 7) << 4))) = vals[j];
                }
            }
            __syncthreads();
        }
        cur ^= 1;
    }

    // ---- epilogue ----
    const float inv = 1.0f / l_;
    float* op = out + base + (long)iq * DK_;
    #pragma unroll
    for (int rq = 0; rq < 4; ++rq) {
        float4 f0, f1;
        f0.x = O0[rq * 4 + 0] * inv; f0.y = O0[rq * 4 + 1] * inv;
        f0.z = O0[rq * 4 + 2] * inv; f0.w = O0[rq * 4 + 3] * inv;
        f1.x = O1[rq * 4 + 0] * inv; f1.y = O1[rq * 4 + 1] * inv;
        f1.z = O1[rq * 4 + 2] * inv; f1.w = O1[rq * 4 + 3] * inv;
        *(float4*)(op + rq * 8 + hi * 4)      = f0;
        *(float4*)(op + 32 + rq * 8 + hi * 4) = f1;
    }
}

extern "C" void kernel_launch(void* const* d_in, const int* in_sizes, int n_in,
                              void* d_out, int out_size, void* d_ws, size_t ws_size,
                              hipStream_t stream) {
    const float* q = (const float*)d_in[0];
    const float* k = (const float*)d_in[1];
    const float* v = (const float*)d_in[2];
    const int* sen_len = (const int*)d_in[3];
    float* out = (float*)d_out;

    const size_t kv_elems = (size_t)NBH * S_ * DK_;   // 8.39M
    const bool pre = ws_size >= kv_elems * 2 * sizeof(unsigned short);
    unsigned short* kbf  = (unsigned short*)d_ws;
    unsigned short* vtbf = kbf + kv_elems;

    if (pre) {
        conv_k<<<dim3((unsigned)(kv_elems / 2048)), dim3(256), 0, stream>>>(k, kbf);
        transp_v<<<dim3(S_ / 64, NBH), dim3(256), 0, stream>>>(v, vtbf);
        attn_fwd4<true><<<dim3(S_ / 128, NBH), dim3(256), 0, stream>>>(
            q, k, v, kbf, vtbf, sen_len, out);
    } else {
        attn_fwd4<false><<<dim3(S_ / 128, NBH), dim3(256), 0, stream>>>(
            q, k, v, kbf, vtbf, sen_len, out);
    }
}